// Round 4
// baseline (387.102 us; speedup 1.0000x reference)
//
#include <hip/hip_runtime.h>
#include <math.h>

// One WAVE (64 lanes) per output row; 4 rows per 256-thread block.
// No __syncthreads, no LDS: each wave is an independent load->reduce->store
// pipeline. Non-temporal stores keep the 128 MB q_out stream from evicting
// gathered input rows (dup gathers ~1.58x reuse) out of L2/L3.
// d_out layout (all float32): [N*d] quantized values, then [N] quant_scale.

#define THREADS 256

// Native vector type: __builtin_nontemporal_store rejects HIP_vector_type.
typedef float nfloat4 __attribute__((ext_vector_type(4)));

__device__ __forceinline__ float fast_silu(float x) {
    // x * sigmoid(x) = x / (1 + e^-x); v_exp + v_rcp, ~1ulp each.
    float e = __expf(-x);
    return x * __builtin_amdgcn_rcpf(1.0f + e);
}

template <int D>
__global__ __launch_bounds__(THREADS) void swiglu_moe_quant_wave(
    const float* __restrict__ input,            // [N, 2*D]
    const float* __restrict__ smooth_scale,     // [E, D]
    const int*   __restrict__ sorted_token_ids, // [N]
    const int*   __restrict__ topk_indices,     // [N]
    float* __restrict__ q_out,                  // [N, D] quantized (f32)
    float* __restrict__ scale_out,              // [N]
    int N)
{
    constexpr int PER = D / (64 * 4);           // 8 float4 per lane for D=2048

    const int wave = threadIdx.x >> 6;
    const int lane = threadIdx.x & 63;
    const int row  = blockIdx.x * (THREADS / 64) + wave;
    if (row >= N) return;

    const int tok  = sorted_token_ids[row];
    const int exp_ = topk_indices[row];

    const float* g  = input + (size_t)tok * (size_t)(2 * D);
    const float* up = g + D;
    const float* ss = smooth_scale + (size_t)exp_ * (size_t)D;

    float4 act[PER];
    float amax = 0.0f;

    #pragma unroll
    for (int k = 0; k < PER; ++k) {
        const int j = (lane + k * 64) * 4;
        float4 gv = *(const float4*)(g  + j);
        float4 uv = *(const float4*)(up + j);
        float4 sv = *(const float4*)(ss + j);
        float4 a;
        a.x = fast_silu(gv.x) * uv.x * sv.x;
        a.y = fast_silu(gv.y) * uv.y * sv.y;
        a.z = fast_silu(gv.z) * uv.z * sv.z;
        a.w = fast_silu(gv.w) * uv.w * sv.w;
        act[k] = a;
        amax = fmaxf(amax, fmaxf(fmaxf(fabsf(a.x), fabsf(a.y)),
                                 fmaxf(fabsf(a.z), fabsf(a.w))));
    }

    // Butterfly max across the 64-lane wave: every lane ends with the max.
    #pragma unroll
    for (int off = 32; off > 0; off >>= 1)
        amax = fmaxf(amax, __shfl_xor(amax, off));

    const float qs    = (amax > 0.0f) ? (amax / 127.0f) : 1.0f; // IEEE, matches ref
    const float invqs = 1.0f / qs;
    if (lane == 0) scale_out[row] = qs;

    float* qrow = q_out + (size_t)row * (size_t)D;
    #pragma unroll
    for (int k = 0; k < PER; ++k) {
        const int j = (lane + k * 64) * 4;
        float4 a = act[k];
        nfloat4 q;
        q.x = fminf(127.0f, fmaxf(-127.0f, rintf(a.x * invqs)));
        q.y = fminf(127.0f, fmaxf(-127.0f, rintf(a.y * invqs)));
        q.z = fminf(127.0f, fmaxf(-127.0f, rintf(a.z * invqs)));
        q.w = fminf(127.0f, fmaxf(-127.0f, rintf(a.w * invqs)));
        __builtin_nontemporal_store(q, (nfloat4*)(qrow + j));
    }
}

// Generic fallback for d != 2048 (bench shape is always 2048).
__global__ __launch_bounds__(THREADS) void swiglu_moe_quant_generic(
    const float* __restrict__ input,
    const float* __restrict__ smooth_scale,
    const int*   __restrict__ sorted_token_ids,
    const int*   __restrict__ topk_indices,
    float* __restrict__ q_out,
    float* __restrict__ scale_out,
    int d)
{
    const int row  = blockIdx.x;
    const int tok  = sorted_token_ids[row];
    const int exp_ = topk_indices[row];
    const float* g  = input + (size_t)tok * (size_t)(2 * d);
    const float* up = g + d;
    const float* ss = smooth_scale + (size_t)exp_ * (size_t)d;
    const int t = threadIdx.x;

    float amax = 0.0f;
    for (int j = t; j < d; j += THREADS) {
        float a = fast_silu(g[j]) * up[j] * ss[j];
        amax = fmaxf(amax, fabsf(a));
    }
    #pragma unroll
    for (int off = 32; off > 0; off >>= 1)
        amax = fmaxf(amax, __shfl_down(amax, off));
    __shared__ float wave_max[THREADS / 64];
    if ((t & 63) == 0) wave_max[t >> 6] = amax;
    __syncthreads();
    float m = fmaxf(fmaxf(wave_max[0], wave_max[1]),
                    fmaxf(wave_max[2], wave_max[3]));
    const float qs    = (m > 0.0f) ? (m / 127.0f) : 1.0f;
    const float invqs = 1.0f / qs;
    if (t == 0) scale_out[row] = qs;
    float* qrow = q_out + (size_t)row * (size_t)d;
    for (int j = t; j < d; j += THREADS) {
        float a = fast_silu(g[j]) * up[j] * ss[j];
        qrow[j] = fminf(127.0f, fmaxf(-127.0f, rintf(a * invqs)));
    }
}

extern "C" void kernel_launch(void* const* d_in, const int* in_sizes, int n_in,
                              void* d_out, int out_size, void* d_ws, size_t ws_size,
                              hipStream_t stream) {
    const float* input        = (const float*)d_in[0];
    const float* smooth_scale = (const float*)d_in[1];
    const int*   sorted_ids   = (const int*)d_in[2];
    const int*   topk_idx     = (const int*)d_in[3];

    const int N   = in_sizes[2];            // 16384
    const int FC1 = in_sizes[0] / N;        // 4096
    const int d   = FC1 / 2;                // 2048

    float* q_out     = (float*)d_out;
    float* scale_out = (float*)d_out + (size_t)N * (size_t)d;

    if (d == 2048) {
        const int rows_per_block = THREADS / 64;                 // 4
        const int blocks = (N + rows_per_block - 1) / rows_per_block;
        swiglu_moe_quant_wave<2048><<<blocks, THREADS, 0, stream>>>(
            input, smooth_scale, sorted_ids, topk_idx, q_out, scale_out, N);
    } else {
        swiglu_moe_quant_generic<<<N, THREADS, 0, stream>>>(
            input, smooth_scale, sorted_ids, topk_idx, q_out, scale_out, d);
    }
}